// Round 10
// baseline (492.989 us; speedup 1.0000x reference)
//
#include <hip/hip_runtime.h>

typedef short short8 __attribute__((ext_vector_type(8)));
typedef float f32x4  __attribute__((ext_vector_type(4)));
typedef unsigned short u16;

#define T_LEN 256
#define NB    8            // samples per block
#define GRID  (2048 / NB)  // 256 blocks, 1/CU
#define LDK   72           // row stride in u16 for 64-col buffers (144 B)

static __device__ __forceinline__ u16 bf16_rne(float f) {
    unsigned u = __builtin_bit_cast(unsigned, f);
    return (u16)((u + 0x7fffu + ((u >> 16) & 1u)) >> 16);
}
static __device__ __forceinline__ float bf16_f(u16 h) {
    unsigned u = ((unsigned)h) << 16;
    return __builtin_bit_cast(float, u);
}
// exact trunc split: f == bf16(hi) + rest; lo = trunc-bf16(rest)
static __device__ __forceinline__ void split_tr(float f, u16& hi, u16& lo) {
    unsigned u = __builtin_bit_cast(unsigned, f);
    hi = (u16)(u >> 16);
    float rest = f - __builtin_bit_cast(float, u & 0xffff0000u);
    lo = (u16)(__builtin_bit_cast(unsigned, rest) >> 16);
}
static __device__ __forceinline__ float fast_sigmoid(float x) {
    float e = __builtin_amdgcn_exp2f(x * -1.4426950408889634f);
    return __builtin_amdgcn_rcpf(1.0f + e);
}
static __device__ __forceinline__ float fast_tanh(float x) {
    float e = __builtin_amdgcn_exp2f(x * -2.8853900817779268f);
    return 2.0f * __builtin_amdgcn_rcpf(1.0f + e) - 1.0f;
}

// ---------------------------------------------------------------------------
// 16-wave wave-specialized fused 2-layer LSTM + FC, split-bf16 MFMA,
// lo-in-columns, shared-H1 buffers, 2-step-unrolled (compile-time parity,
// hoisted LDS base pointers), staging on grp1.
//   XB[p]: [x(t)]    rows 0-7 hi / 8-15 lo (staged by grp1)
//   H1[p]: [h1(t-1)] same layout (written once by grp0)
//   H2[p]: [h2(t-2)] same layout (written by grp1)
// grp0 (waves 0-7):  B = [XB|H1], layer 0 step t
// grp1 (waves 8-15): B = [H1|H2], layer 1 step t-1, + x staging
// Per (mt): aH = Ah x B; aL = Al x B + bias;
// gates(s) = aH[:,s] + aH[:,s+8] + aL[:,s] via one shfl_xor(8) per C row.
// Row permutation (verified r4-r9): row = gate*64 + unit, unit = wl*8+mt*4+uu,
// uu = ln>>2, gate = ln&3; C: col=ln, acc[r] = gate r of unit wl*8+mt*4+kg.
// Packed lane identity: smp = ln&7, un = wl*8 + ((ln>>3)&1)*4 + kg.
// ---------------------------------------------------------------------------
__global__ __launch_bounds__(1024)
void lstm2_mfma(const float* __restrict__ x,
                const float* __restrict__ W_ih0, const float* __restrict__ W_hh0,
                const float* __restrict__ b_ih0, const float* __restrict__ b_hh0,
                const float* __restrict__ W_ih1, const float* __restrict__ W_hh1,
                const float* __restrict__ b_ih1, const float* __restrict__ b_hh1,
                const float* __restrict__ fc_w,  const float* __restrict__ fc_b,
                float* __restrict__ out)
{
    const int tid = threadIdx.x;
    const int l   = tid & 63;
    const int w   = tid >> 6;      // wave 0..15
    const int grp = w >> 3;        // 0 = layer0, 1 = layer1
    const int wl  = w & 7;         // wave-in-group 0..7
    const int ln  = l & 15;        // C col / frag row
    const int kg  = l >> 4;        // 0..3

    __shared__ __align__(16) u16 XB[2][16][LDK];
    __shared__ __align__(16) u16 H1[2][16][LDK];
    __shared__ __align__(16) u16 H2[2][16][LDK];
    __shared__ __align__(16) float hfin[NB][68];

    // ---- A fragments (my layer, 2 mtiles): RNE hi + lo ----
    short8 Ah[2][4], Al[2][4];
    f32x4  biasv[2];
    {
        const float* Wi = grp ? W_ih1 : W_ih0;
        const float* Wh = grp ? W_hh1 : W_hh0;
        const float* bi = grp ? b_ih1 : b_ih0;
        const float* bh = grp ? b_hh1 : b_hh0;
        #pragma unroll
        for (int mt = 0; mt < 2; ++mt) {
            #pragma unroll
            for (int kt = 0; kt < 4; ++kt) {
                const int uu   = ln >> 2;
                const int gate = ln & 3;
                const int row  = gate * 64 + (wl * 8 + mt * 4 + uu);
                const int kb   = kt * 32 + kg * 8;
                const float* src = (kb < 64) ? (Wi + (size_t)row * 64 + kb)
                                             : (Wh + (size_t)row * 64 + (kb - 64));
                short8 h8, l8;
                #pragma unroll
                for (int j = 0; j < 8; ++j) {
                    float v = src[j];
                    u16 hh = bf16_rne(v);
                    u16 ll = bf16_rne(v - bf16_f(hh));
                    h8[j] = (short)hh; l8[j] = (short)ll;
                }
                Ah[mt][kt] = h8; Al[mt][kt] = l8;
            }
            f32x4 bv;
            #pragma unroll
            for (int r = 0; r < 4; ++r) {
                const int row = r * 64 + (wl * 8 + mt * 4 + kg);
                bv[r] = bi[row] + bh[row];
            }
            biasv[mt] = bv;
        }
    }

    // ---- zero operand LDS (h states start at 0) ----
    {
        u16* p0 = &XB[0][0][0];
        u16* p1 = &H1[0][0][0];
        u16* p2 = &H2[0][0][0];
        const int tot = 2 * 16 * LDK;
        for (int i = tid; i < tot; i += 1024) { p0[i] = 0; p1[i] = 0; p2[i] = 0; }
    }
    __syncthreads();

    const int    sb    = blockIdx.x * NB;
    const bool   stg   = (grp == 1);    // staging on layer-1 waves (balance)
    const int    xs    = wl;
    const int    xj    = l;
    const size_t xbase = ((size_t)(sb + xs)) * T_LEN * 64 + xj;

    if (stg) {   // stage x(0) into XB[0]
        u16 hh, ll; split_tr(x[xbase], hh, ll);
        XB[0][xs][xj]     = hh;
        XB[0][8 + xs][xj] = ll;
    }
    __syncthreads();

    // packed-lane identity for activations/updates
    const int  mtl  = (ln >> 3) & 1;       // 0: mt0 value, 1: mt1 value
    const int  smp  = ln & 7;              // sample
    const int  un   = wl * 8 + mtl * 4 + kg;
    const bool lo8  = (ln < 8);
    float cstate = 0.f;
    float xcur = stg ? x[xbase + 64] : 0.f;   // x(1)
    const float* xp = x + xbase + 2 * 64;     // x(t+2) rolling ptr (grp1 only)

    // ---- hoisted LDS base pointers (select once) ----
    const u16* rdA0 = grp ? &H1[0][ln][kg * 8] : &XB[0][ln][kg * 8];
    const u16* rdA1 = grp ? &H1[1][ln][kg * 8] : &XB[1][ln][kg * 8];
    const u16* rdB0 = grp ? &H2[0][ln][kg * 8] : &H1[0][ln][kg * 8];
    const u16* rdB1 = grp ? &H2[1][ln][kg * 8] : &H1[1][ln][kg * 8];
    u16* wr0 = grp ? &H2[0][smp][un] : &H1[0][smp][un];   // write parity 0
    u16* wr1 = grp ? &H2[1][smp][un] : &H1[1][smp][un];   // write parity 1
    u16* sx0 = &XB[0][xs][xj];
    u16* sx1 = &XB[1][xs][xj];

#define MFMA(A, B, C) __builtin_amdgcn_mfma_f32_16x16x32_bf16(A, B, C, 0, 0, 0)

// STEP(T): reads parity-P bases rdA/rdB, writes parity-Q wrh, stages into sxh.
#define STEP(T, rdA, rdB, wrh, sxh)                                          \
    do {                                                                     \
        const bool act_ = grp ? ((T) >= 1) : ((T) < T_LEN);                  \
        float xnext_ = 0.f;                                                  \
        if (stg && (T) + 2 < T_LEN) xnext_ = *xp;                            \
        short8 b0, b1, b2, b3;                                               \
        if (act_) {                                                          \
            b0 = *(const short8*)(rdA);                                      \
            b1 = *(const short8*)((rdA) + 32);                               \
            b2 = *(const short8*)(rdB);                                      \
            b3 = *(const short8*)((rdB) + 32);                               \
        }                                                                    \
        if (stg && (T) + 1 < T_LEN) {   /* fill ds_read latency */           \
            u16 hh_, ll_; split_tr(xcur, hh_, ll_);                          \
            (sxh)[0] = hh_; (sxh)[8 * LDK] = ll_;                            \
        }                                                                    \
        if (act_) {                                                          \
            f32x4 aH0 = {0.f,0.f,0.f,0.f}, aH1 = {0.f,0.f,0.f,0.f};          \
            f32x4 aL0 = biasv[0],          aL1 = biasv[1];                   \
            aH0 = MFMA(Ah[0][0], b0, aH0);  aH1 = MFMA(Ah[1][0], b0, aH1);   \
            aL0 = MFMA(Al[0][0], b0, aL0);  aL1 = MFMA(Al[1][0], b0, aL1);   \
            aH0 = MFMA(Ah[0][1], b1, aH0);  aH1 = MFMA(Ah[1][1], b1, aH1);   \
            aL0 = MFMA(Al[0][1], b1, aL0);  aL1 = MFMA(Al[1][1], b1, aL1);   \
            aH0 = MFMA(Ah[0][2], b2, aH0);  aH1 = MFMA(Ah[1][2], b2, aH1);   \
            aL0 = MFMA(Al[0][2], b2, aL0);  aL1 = MFMA(Al[1][2], b2, aL1);   \
            aH0 = MFMA(Ah[0][3], b3, aH0);  aH1 = MFMA(Ah[1][3], b3, aH1);   \
            aL0 = MFMA(Al[0][3], b3, aL0);  aL1 = MFMA(Al[1][3], b3, aL1);   \
            f32x4 pk;                                                        \
            _Pragma("unroll")                                                \
            for (int r = 0; r < 4; ++r) {                                    \
                float send = lo8 ? (aH1[r] + aL1[r]) : aH0[r];               \
                float recv = __shfl_xor(send, 8, 64);                        \
                pk[r] = lo8 ? (aH0[r] + recv + aL0[r]) : (aH1[r] + recv);    \
            }                                                                \
            const float ig = fast_sigmoid(pk[0]);                            \
            const float fg = fast_sigmoid(pk[1]);                            \
            const float gg = fast_tanh(pk[2]);                               \
            const float og = fast_sigmoid(pk[3]);                            \
            const float cc = fg * cstate + ig * gg;                          \
            cstate = cc;                                                     \
            const float hv = og * fast_tanh(cc);                             \
            u16 hh_, ll_; split_tr(hv, hh_, ll_);                            \
            (wrh)[0] = hh_; (wrh)[8 * LDK] = ll_;                            \
            if (grp && (T) == T_LEN) hfin[smp][un] = hv;                     \
        }                                                                    \
        xcur = xnext_;                                                       \
        xp += 64;                                                            \
        __syncthreads();                                                     \
    } while (0)

    // t = 0 (read parity 0, write parity 1)
    STEP(0, rdA0, rdB0, wr1, sx1);
    // t = 1..256 in pairs: odd t reads parity 1 / writes 0; even reads 0 / writes 1
    #pragma unroll 1
    for (int t = 1; t < T_LEN; t += 2) {
        STEP(t,     rdA1, rdB1, wr0, sx0);
        STEP(t + 1, rdA0, rdB0, wr1, sx1);
    }
#undef STEP
#undef MFMA

    // ---- FC head: waves 0-7, wave w reduces sample w ----
    if (w < 8) {
        float v = hfin[w][l] * fc_w[l];
        #pragma unroll
        for (int off = 32; off; off >>= 1) v += __shfl_xor(v, off, 64);
        if (l == 0) out[sb + w] = v + fc_b[0];
    }
}

extern "C" void kernel_launch(void* const* d_in, const int* in_sizes, int n_in,
                              void* d_out, int out_size, void* d_ws, size_t ws_size,
                              hipStream_t stream) {
    const float* x     = (const float*)d_in[0];
    const float* W_ih0 = (const float*)d_in[1];
    const float* W_hh0 = (const float*)d_in[2];
    const float* b_ih0 = (const float*)d_in[3];
    const float* b_hh0 = (const float*)d_in[4];
    const float* W_ih1 = (const float*)d_in[5];
    const float* W_hh1 = (const float*)d_in[6];
    const float* b_ih1 = (const float*)d_in[7];
    const float* b_hh1 = (const float*)d_in[8];
    const float* fc_w  = (const float*)d_in[9];
    const float* fc_b  = (const float*)d_in[10];
    float* out = (float*)d_out;

    lstm2_mfma<<<GRID, 1024, 0, stream>>>(x, W_ih0, W_hh0, b_ih0, b_hh0,
                                          W_ih1, W_hh1, b_ih1, b_hh1,
                                          fc_w, fc_b, out);
}

// Round 11
// 263.920 us; speedup vs baseline: 1.8679x; 1.8679x over previous
//
#include <hip/hip_runtime.h>

typedef short short8 __attribute__((ext_vector_type(8)));
typedef float f32x4  __attribute__((ext_vector_type(4)));
typedef unsigned short u16;

#define T_LEN 256
#define NB    8            // samples per block
#define GRID  (2048 / NB)  // 256 blocks, 1/CU
#define LDK   72           // row stride in u16 for 64-col buffers (144 B)

static __device__ __forceinline__ u16 bf16_rne(float f) {
    unsigned u = __builtin_bit_cast(unsigned, f);
    return (u16)((u + 0x7fffu + ((u >> 16) & 1u)) >> 16);
}
static __device__ __forceinline__ float bf16_f(u16 h) {
    unsigned u = ((unsigned)h) << 16;
    return __builtin_bit_cast(float, u);
}
// exact trunc split: f == bf16(hi) + rest; lo = trunc-bf16(rest)
static __device__ __forceinline__ void split_tr(float f, u16& hi, u16& lo) {
    unsigned u = __builtin_bit_cast(unsigned, f);
    hi = (u16)(u >> 16);
    float rest = f - __builtin_bit_cast(float, u & 0xffff0000u);
    lo = (u16)(__builtin_bit_cast(unsigned, rest) >> 16);
}
static __device__ __forceinline__ float fast_sigmoid(float x) {
    float e = __builtin_amdgcn_exp2f(x * -1.4426950408889634f);
    return __builtin_amdgcn_rcpf(1.0f + e);
}
static __device__ __forceinline__ float fast_tanh(float x) {
    float e = __builtin_amdgcn_exp2f(x * -2.8853900817779268f);
    return 2.0f * __builtin_amdgcn_rcpf(1.0f + e) - 1.0f;
}

// ---------------------------------------------------------------------------
// 16-wave wave-specialized fused 2-layer LSTM + FC, split-bf16 MFMA,
// lo-in-columns, shared-H1 buffers (r9 body), NO setprio, boundary steps
// peeled so the main loop (t=1..253) is branch-free and fully active.
// LDS accesses stay direct __shared__-array expressions (r10 lesson: hoisted
// generic pointers lowered to flat_load and doubled runtime).
//   XB[p]: [x(t)]    rows 0-7 hi / 8-15 lo (staged by grp0 threads)
//   H1[p]: [h1(t-1)] same layout (written once by grp0)
//   H2[p]: [h2(t-2)] same layout (written by grp1)
// grp0 (waves 0-7):  B = [XB|H1], layer 0 step t, + x staging
// grp1 (waves 8-15): B = [H1|H2], layer 1 step t-1
// Per (mt): aH = Ah x B; aL = Al x B + bias;
// gates(s) = aH[:,s] + aH[:,s+8] + aL[:,s] via one shfl_xor(8) per C row.
// Row permutation (verified r4-r9): row = gate*64 + unit, unit = wl*8+mt*4+uu,
// uu = ln>>2, gate = ln&3; C: col=ln, acc[r] = gate r of unit wl*8+mt*4+kg.
// Packed lane identity: smp = ln&7, un = wl*8 + ((ln>>3)&1)*4 + kg.
// ---------------------------------------------------------------------------
__global__ __launch_bounds__(1024)
void lstm2_mfma(const float* __restrict__ x,
                const float* __restrict__ W_ih0, const float* __restrict__ W_hh0,
                const float* __restrict__ b_ih0, const float* __restrict__ b_hh0,
                const float* __restrict__ W_ih1, const float* __restrict__ W_hh1,
                const float* __restrict__ b_ih1, const float* __restrict__ b_hh1,
                const float* __restrict__ fc_w,  const float* __restrict__ fc_b,
                float* __restrict__ out)
{
    const int tid = threadIdx.x;
    const int l   = tid & 63;
    const int w   = tid >> 6;      // wave 0..15
    const int grp = w >> 3;        // 0 = layer0, 1 = layer1
    const int wl  = w & 7;         // wave-in-group 0..7
    const int ln  = l & 15;        // C col / frag row
    const int kg  = l >> 4;        // 0..3

    __shared__ __align__(16) u16 XB[2][16][LDK];
    __shared__ __align__(16) u16 H1[2][16][LDK];
    __shared__ __align__(16) u16 H2[2][16][LDK];
    __shared__ __align__(16) float hfin[NB][68];

    // ---- A fragments (my layer, 2 mtiles): RNE hi + lo ----
    short8 Ah[2][4], Al[2][4];
    f32x4  biasv[2];
    {
        const float* Wi = grp ? W_ih1 : W_ih0;
        const float* Wh = grp ? W_hh1 : W_hh0;
        const float* bi = grp ? b_ih1 : b_ih0;
        const float* bh = grp ? b_hh1 : b_hh0;
        #pragma unroll
        for (int mt = 0; mt < 2; ++mt) {
            #pragma unroll
            for (int kt = 0; kt < 4; ++kt) {
                const int uu   = ln >> 2;
                const int gate = ln & 3;
                const int row  = gate * 64 + (wl * 8 + mt * 4 + uu);
                const int kb   = kt * 32 + kg * 8;
                const float* src = (kb < 64) ? (Wi + (size_t)row * 64 + kb)
                                             : (Wh + (size_t)row * 64 + (kb - 64));
                short8 h8, l8;
                #pragma unroll
                for (int j = 0; j < 8; ++j) {
                    float v = src[j];
                    u16 hh = bf16_rne(v);
                    u16 ll = bf16_rne(v - bf16_f(hh));
                    h8[j] = (short)hh; l8[j] = (short)ll;
                }
                Ah[mt][kt] = h8; Al[mt][kt] = l8;
            }
            f32x4 bv;
            #pragma unroll
            for (int r = 0; r < 4; ++r) {
                const int row = r * 64 + (wl * 8 + mt * 4 + kg);
                bv[r] = bi[row] + bh[row];
            }
            biasv[mt] = bv;
        }
    }

    // ---- zero operand LDS (h states start at 0) ----
    {
        u16* p0 = &XB[0][0][0];
        u16* p1 = &H1[0][0][0];
        u16* p2 = &H2[0][0][0];
        const int tot = 2 * 16 * LDK;
        for (int i = tid; i < tot; i += 1024) { p0[i] = 0; p1[i] = 0; p2[i] = 0; }
    }
    __syncthreads();

    const int    sb    = blockIdx.x * NB;
    const int    xs    = (tid >> 6) & 7;   // staging sample (threads 0..511)
    const int    xj    = tid & 63;
    const bool   stg   = (tid < 512);      // wave-uniform (grp0 stages)
    const size_t xbase = ((size_t)(sb + xs)) * T_LEN * 64 + xj;

    if (stg) {   // stage x(0) into XB[0]
        u16 hh, ll; split_tr(x[xbase], hh, ll);
        XB[0][xs][xj]     = hh;
        XB[0][8 + xs][xj] = ll;
    }
    __syncthreads();

    // packed-lane identity for activations/updates
    const int  mtl  = (ln >> 3) & 1;       // 0: mt0 value, 1: mt1 value
    const int  smp  = ln & 7;              // sample
    const int  un   = wl * 8 + mtl * 4 + kg;
    const bool lo8  = (ln < 8);
    float cstate = 0.f;
    float xcur = stg ? x[xbase + 64] : 0.f;   // x(1)

#define MFMA(A, B, C) __builtin_amdgcn_mfma_f32_16x16x32_bf16(A, B, C, 0, 0, 0)

// STEPB(T, G0, G1, STG_ON, XLOAD, FIN): G0/G1 = group active (compile-time),
// STG_ON = stage x(T+1), XLOAD = prefetch x(T+2), FIN = record hfin (grp1).
#define STEPB(T, G0, G1, STG_ON, XLOAD, FIN)                                 \
    do {                                                                     \
        const int p_ = (T) & 1, q_ = p_ ^ 1;                                 \
        float xnext_ = 0.f;                                                  \
        if ((XLOAD) && stg) xnext_ = x[xbase + (size_t)((T) + 2) * 64];      \
        const bool act_ = grp ? (bool)(G1) : (bool)(G0);                     \
        if (act_) {                                                          \
            const u16 (*BA)[LDK] = grp ? H1[p_] : XB[p_];                    \
            const u16 (*BB)[LDK] = grp ? H2[p_] : H1[p_];                    \
            short8 b0 = *(const short8*)&BA[ln][kg * 8];                     \
            short8 b1 = *(const short8*)&BA[ln][32 + kg * 8];                \
            short8 b2 = *(const short8*)&BB[ln][kg * 8];                     \
            short8 b3 = *(const short8*)&BB[ln][32 + kg * 8];                \
            f32x4 aH0 = {0.f,0.f,0.f,0.f}, aH1 = {0.f,0.f,0.f,0.f};          \
            f32x4 aL0 = biasv[0],          aL1 = biasv[1];                   \
            aH0 = MFMA(Ah[0][0], b0, aH0);  aH1 = MFMA(Ah[1][0], b0, aH1);   \
            aL0 = MFMA(Al[0][0], b0, aL0);  aL1 = MFMA(Al[1][0], b0, aL1);   \
            aH0 = MFMA(Ah[0][1], b1, aH0);  aH1 = MFMA(Ah[1][1], b1, aH1);   \
            aL0 = MFMA(Al[0][1], b1, aL0);  aL1 = MFMA(Al[1][1], b1, aL1);   \
            aH0 = MFMA(Ah[0][2], b2, aH0);  aH1 = MFMA(Ah[1][2], b2, aH1);   \
            aL0 = MFMA(Al[0][2], b2, aL0);  aL1 = MFMA(Al[1][2], b2, aL1);   \
            aH0 = MFMA(Ah[0][3], b3, aH0);  aH1 = MFMA(Ah[1][3], b3, aH1);   \
            aL0 = MFMA(Al[0][3], b3, aL0);  aL1 = MFMA(Al[1][3], b3, aL1);   \
            f32x4 pk;                                                        \
            _Pragma("unroll")                                                \
            for (int r = 0; r < 4; ++r) {                                    \
                float send = lo8 ? (aH1[r] + aL1[r]) : aH0[r];               \
                float recv = __shfl_xor(send, 8, 64);                        \
                pk[r] = lo8 ? (aH0[r] + recv + aL0[r]) : (aH1[r] + recv);    \
            }                                                                \
            const float ig = fast_sigmoid(pk[0]);                            \
            const float fg = fast_sigmoid(pk[1]);                            \
            const float gg = fast_tanh(pk[2]);                               \
            const float og = fast_sigmoid(pk[3]);                            \
            const float cc = fg * cstate + ig * gg;                          \
            cstate = cc;                                                     \
            const float hv = og * fast_tanh(cc);                             \
            u16 hh_, ll_; split_tr(hv, hh_, ll_);                            \
            if (grp == 0) {                                                  \
                H1[q_][smp][un]     = hh_;                                   \
                H1[q_][8 + smp][un] = ll_;                                   \
            } else {                                                         \
                H2[q_][smp][un]     = hh_;                                   \
                H2[q_][8 + smp][un] = ll_;                                   \
                if (FIN) hfin[smp][un] = hv;                                 \
            }                                                                \
        }                                                                    \
        if ((STG_ON) && stg) {                                               \
            u16 hh_, ll_; split_tr(xcur, hh_, ll_);                          \
            XB[q_][xs][xj]     = hh_;                                        \
            XB[q_][8 + xs][xj] = ll_;                                        \
        }                                                                    \
        xcur = xnext_;                                                       \
        __syncthreads();                                                     \
    } while (0)

    // t = 0: grp0 only; stage x(1); prefetch x(2)
    STEPB(0, 1, 0, 1, 1, 0);
    // main loop t = 1..253: both groups, staging + prefetch, branch-free
    #pragma unroll 1
    for (int t = 1; t <= 253; ++t) {
        STEPB(t, 1, 1, 1, 1, 0);
    }
    // t = 254: both groups, stage x(255), no further prefetch
    STEPB(254, 1, 1, 1, 0, 0);
    // t = 255: both groups, no staging
    STEPB(255, 1, 1, 0, 0, 0);
    // t = 256: grp1 finishes layer-1 step 255, records hfin
    STEPB(256, 0, 1, 0, 0, 1);
#undef STEPB
#undef MFMA

    // ---- FC head: waves 0-7, wave w reduces sample w ----
    if (w < 8) {
        float v = hfin[w][l] * fc_w[l];
        #pragma unroll
        for (int off = 32; off; off >>= 1) v += __shfl_xor(v, off, 64);
        if (l == 0) out[sb + w] = v + fc_b[0];
    }
}

extern "C" void kernel_launch(void* const* d_in, const int* in_sizes, int n_in,
                              void* d_out, int out_size, void* d_ws, size_t ws_size,
                              hipStream_t stream) {
    const float* x     = (const float*)d_in[0];
    const float* W_ih0 = (const float*)d_in[1];
    const float* W_hh0 = (const float*)d_in[2];
    const float* b_ih0 = (const float*)d_in[3];
    const float* b_hh0 = (const float*)d_in[4];
    const float* W_ih1 = (const float*)d_in[5];
    const float* W_hh1 = (const float*)d_in[6];
    const float* b_ih1 = (const float*)d_in[7];
    const float* b_hh1 = (const float*)d_in[8];
    const float* fc_w  = (const float*)d_in[9];
    const float* fc_b  = (const float*)d_in[10];
    float* out = (float*)d_out;

    lstm2_mfma<<<GRID, 1024, 0, stream>>>(x, W_ih0, W_hh0, b_ih0, b_hh0,
                                          W_ih1, W_hh1, b_ih1, b_hh1,
                                          fc_w, fc_b, out);
}